// Round 11
// baseline (76.705 us; speedup 1.0000x reference)
//
#include <hip/hip_runtime.h>

typedef __attribute__((ext_vector_type(8))) short short8;
typedef __attribute__((ext_vector_type(4))) float float4v;

#define TPB 256
#define NPART 3207168            /* partial floats: 8 kc-slices (in-block kh-reduced) */
#define NOUT  739840             /* 640*4*289 */

// per-partial-tile base (floats), 19 tiles. size(t) = 8*4*DYN*MV*16
__device__ __constant__ int TBASE[19] = {
    0, 278528, 557056, 835584, 1114112, 1392640, 1671168, 1949696, 2228224,
    2506752, 2617344, 2727936, 2838528, 2949120,
    3059712, 3100672, 3141632,
    3182592, 3194880};
__device__ __constant__ unsigned char J1T[10] = {0,0,0,0,1,1,1,2,2,3};
__device__ __constant__ unsigned char J2T[10] = {0,1,2,3,1,2,3,2,3,3};
__device__ __constant__ unsigned char TSTART[4] = {17,14,9,0};   // class->first tile

static __device__ __forceinline__ unsigned short f2bf(float f) {
    unsigned int u = __builtin_bit_cast(unsigned int, f);
    u = (u + 0x7FFFu + ((u >> 16) & 1u)) >> 16;     // RNE, data has no NaN
    return (unsigned short)u;
}

// corr[p,b,dx,dy] = sum_{u,v} a[u,v]*b[(u-dx)%128,(v-dy)%128]; |dx|,|dy|<=r=2^j2.
// Wave (dg,kh): dg = dyi half (acc 9 slots max -> 36 VGPR), kh = K half (4 slices/sub).
// kh-pairs cross-wave summed via LDS; fp32->bf16 staged in-kernel (T14 split).
template<int J2, bool PART>
static __device__ __forceinline__ void corr_body(
        const float* __restrict__ xpsi,
        float* __restrict__ out, float* __restrict__ part,
        unsigned char* smem, int tgl, int n0, int moff, int b, int kc)
{
    constexpr int R    = 1 << J2;
    constexpr int DXN  = 2 * R + 1;
    constexpr int DYN  = DXN;
    constexpr int NH   = (DYN + 1) / 2;           // dg=0 count
    constexpr int ND2  = DYN - NH;                // dg=1 count
    constexpr int MV   = 8 * (J2 + 1);
    constexpr int ROWS = 16 + 2 * R;
    constexpr int ABUF = 16 * 256;                // A buffer elements (16r x 2K x 128)
    constexpr int S    = DYN * MV * 16;           // floats per partial slice
    constexpr int W    = (J2 == 0) ? 8 : 16;

    unsigned short* a_lds = (unsigned short*)smem;               // 2 x 8KB
    unsigned short* b_lds = (unsigned short*)(smem + 4 * ABUF);

    const int k0    = kc * 16;
    const int vrows = (MV - moff < 16) ? MV - moff : 16;

    const int ch2lo = n0 / DXN;
    int nhi = n0 + W - 1; if (nhi > 8 * DXN - 1) nhi = 8 * DXN - 1;
    const int nimg = nhi / DXN - ch2lo + 1;

    const int tid  = threadIdx.x;
    const int lane = tid & 63;
    const int wv   = tid >> 6;
    const int kh   = wv & 1;          // K half: slices kh*4 .. kh*4+3
    const int dg   = wv >> 1;         // dyi half
    const int c    = lane & 15;       // N-col / A m-row
    const int g    = lane >> 4;       // K-group

    const int ncol    = n0 + c;
    const bool validn = (ncol < 8 * DXN) && (J2 > 0 || c < 8);
    const int ncc     = validn ? ncol : n0;
    const int ch2     = ncc / DXN;
    const int dxi     = ncc - ch2 * DXN;
    const int dx      = dxi - R;
    const int xo      = dx < 0 ? dx + 17 : dx;
    const int bst     = ((ch2 - ch2lo) * ROWS + (2 * R - dxi)) * 152;

    // ---- A stage, split load/write (T14); 16 rows x [2 K-rows x 128px],
    // 16B-granule swizzle lo=(o&31)^ms ----
    float4 ar[4];
    auto loadA = [&](int sub) {
        #pragma unroll
        for (int it = 0; it < 2; ++it) {
            const int o  = it * TPB + tid;
            const int ms = o >> 5;
            const int lo = (o & 31) ^ ms;
            const int me = moff + ms;
            const int j1 = me >> 3, ch1 = me & 7;
            if (ms < vrows) {
                const float* s = xpsi + ((((size_t)j1*4 + b)*8) + ch1) * 16384
                               + (k0 + sub * 2 + (lo >> 4)) * 128 + ((lo & 15) << 3);
                ar[2*it]   = ((const float4*)s)[0];
                ar[2*it+1] = ((const float4*)s)[1];
            } else {
                ar[2*it] = float4{0.f,0.f,0.f,0.f}; ar[2*it+1] = float4{0.f,0.f,0.f,0.f};
            }
        }
    };
    auto writeA = [&](int bufi) {
        unsigned short* ab = a_lds + bufi * ABUF;
        #pragma unroll
        for (int it = 0; it < 2; ++it) {
            const int o = it * TPB + tid;
            const float4 f0 = ar[2*it], f1 = ar[2*it+1];
            *(ushort4*)(ab + o*8)   = ushort4{f2bf(f0.x),f2bf(f0.y),f2bf(f0.z),f2bf(f0.w)};
            *(ushort4*)(ab + o*8+4) = ushort4{f2bf(f1.x),f2bf(f1.y),f2bf(f1.z),f2bf(f1.w)};
        }
    };

    loadA(0);

    // ---- stage B once: [nimg][ROWS][144 +8pad], col tc <-> src (tc+R-16)&127 ----
    if (J2 >= 2) {
        for (int ci = 0; ci < nimg; ++ci) {
            const float* img = xpsi + ((((size_t)J2*4 + b)*8) + ch2lo + ci) * 16384;
            const int ng2 = ROWS * 36;
            for (int i = tid; i < ng2; i += TPB) {
                const int tr = i / 36, tc = (i - tr * 36) * 4;
                const int sr = (k0 - R + tr) & 127;
                const int sc = (tc + R - 16) & 127;
                const float4 v = *(const float4*)(img + sr * 128 + sc);
                *(ushort4*)(b_lds + (ci * ROWS + tr) * 152 + tc) =
                    ushort4{f2bf(v.x), f2bf(v.y), f2bf(v.z), f2bf(v.w)};
            }
        }
    } else {
        const int tot = nimg * ROWS * 144;
        for (int i = tid; i < tot; i += TPB) {
            const int ci = i / (ROWS * 144);
            const int rr = i - ci * (ROWS * 144);
            const int tr = rr / 144, tc = rr - tr * 144;
            const int sr = (k0 - R + tr) & 127;
            const int sc = (tc + R - 16) & 127;
            b_lds[(ci * ROWS + tr) * 152 + tc] =
                f2bf(xpsi[((((size_t)J2*4 + b)*8) + ch2lo + ci) * 16384 + sr * 128 + sc]);
        }
    }

    writeA(0);

    float4v acc[NH];
    #pragma unroll
    for (int i = 0; i < NH; ++i) acc[i] = (float4v)0.f;

    auto compute = [&](int sub, int bufi) {
        const char* abase = (const char*)(a_lds + bufi * ABUF);
        #pragma unroll
        for (int i2 = 0; i2 < 4; ++i2) {          // K-slice = kh*4 + i2
            const int loff = (((kh << 8) | (i2 << 6) | (g << 4))) ^ (c << 4);
            const short8 af0 = *(const short8*)(abase + c * 512 + loff);

            const unsigned short* bp = b_lds + bst + (sub*2 + kh)*152 + (i2<<5) + (g<<3);
            const uint4 wA = *(const uint4*)bp;
            const uint4 wB = *(const uint4*)(bp + 8);
            const uint4 wC = *(const uint4*)(bp + 16);
            const unsigned int wd[12] = {wA.x,wA.y,wA.z,wA.w, wB.x,wB.y,wB.z,wB.w,
                                         wC.x,wC.y,wC.z,wC.w};
            // uniform dg branch keeps extraction constants compile-time (rule #20)
            if (dg == 0) {
                #pragma unroll
                for (int dyl = 0; dyl < NH; ++dyl) {
                    constexpr int base = 0;
                    const int dyi = base + dyl;
                    unsigned int o0,o1,o2,o3;
                    if ((dyi & 1) == 0) {
                        const int bb = 8 - (dyi >> 1);
                        o0=wd[bb]; o1=wd[bb+1]; o2=wd[bb+2]; o3=wd[bb+3];
                    } else {
                        const int bb = (15 - dyi) >> 1;
                        o0=(wd[bb]>>16)|(wd[bb+1]<<16);   o1=(wd[bb+1]>>16)|(wd[bb+2]<<16);
                        o2=(wd[bb+2]>>16)|(wd[bb+3]<<16); o3=(wd[bb+3]>>16)|(wd[bb+4]<<16);
                    }
                    union { unsigned int u[4]; short8 s; } bq;
                    bq.u[0]=o0; bq.u[1]=o1; bq.u[2]=o2; bq.u[3]=o3;
                    acc[dyl] = __builtin_amdgcn_mfma_f32_16x16x32_bf16(
                        af0, bq.s, acc[dyl], 0, 0, 0);
                }
            } else {
                #pragma unroll
                for (int dyl = 0; dyl < ND2; ++dyl) {
                    const int dyi = NH + dyl;
                    unsigned int o0,o1,o2,o3;
                    if ((dyi & 1) == 0) {
                        const int bb = 8 - (dyi >> 1);
                        o0=wd[bb]; o1=wd[bb+1]; o2=wd[bb+2]; o3=wd[bb+3];
                    } else {
                        const int bb = (15 - dyi) >> 1;
                        o0=(wd[bb]>>16)|(wd[bb+1]<<16);   o1=(wd[bb+1]>>16)|(wd[bb+2]<<16);
                        o2=(wd[bb+2]>>16)|(wd[bb+3]<<16); o3=(wd[bb+3]>>16)|(wd[bb+4]<<16);
                    }
                    union { unsigned int u[4]; short8 s; } bq;
                    bq.u[0]=o0; bq.u[1]=o1; bq.u[2]=o2; bq.u[3]=o3;
                    acc[dyl] = __builtin_amdgcn_mfma_f32_16x16x32_bf16(
                        af0, bq.s, acc[dyl], 0, 0, 0);
                }
            }
        }
    };

    __syncthreads();
    for (int sub = 0; sub < 8; ++sub) {
        if (sub < 7) loadA(sub + 1);               // issue next loads (regs)
        compute(sub, sub & 1);
        if (sub < 7) writeA((sub + 1) & 1);        // convert+write after compute
        __syncthreads();
    }

    const int nmine = dg ? ND2 : NH;
    const int dy0   = dg ? NH : 0;

    if (PART) {
        // kh-pair reduction via LDS (<=17.4KB), then direct coalesced-ish stores
        float* red = (float*)smem;                 // [DYN][lane][4] floats
        float* pt  = part + TBASE[tgl] + (size_t)(kc * 4 + b) * S;
        const int cpart0 = n0 & 15;
        if (kh == 1) {
            #pragma unroll
            for (int dyl = 0; dyl < NH; ++dyl) {
                if (dyl >= nmine) break;
                *(float4v*)(red + ((dg * NH + dyl) * 64 + lane) * 4) = acc[dyl];
            }
        }
        __syncthreads();
        if (kh == 0) {
            #pragma unroll
            for (int dyl = 0; dyl < NH; ++dyl) {
                if (dyl >= nmine) break;
                const float4v s = acc[dyl]
                    + *(const float4v*)(red + ((dg * NH + dyl) * 64 + lane) * 4);
                if (validn) {
                    const int dyi = dy0 + dyl;
                    #pragma unroll
                    for (int t2 = 0; t2 < 4; ++t2) {
                        const int ml = (g << 2) + t2;
                        if (ml < vrows)
                            pt[(dyi * MV + moff + ml) * 16 + cpart0 + c] = s[t2];
                    }
                }
            }
        }
        return;
    }

    if (!validn) return;
    #pragma unroll
    for (int dyl = 0; dyl < NH; ++dyl) {
        if (dyl >= nmine) break;
        const int dyi = dy0 + dyl;
        const int dy = dyi - R;
        const int yo = dy < 0 ? dy + 17 : dy;
        #pragma unroll
        for (int t2 = 0; t2 < 4; ++t2) {
            const int ml = (g << 2) + t2;
            if (ml >= vrows) continue;
            const int m = moff + ml;
            const int j1 = m >> 3, ch1 = m & 7;
            const int pb = ((j1 * (9 - j1)) >> 1) + (J2 - j1);
            const int p  = pb * 64 + ((ch1 >> 1) << 4) + ((ch2 >> 1) << 2)
                         + ((ch1 & 1) << 1) + (ch2 & 1);
            atomicAdd(out + (size_t)(p * 4 + b) * 289 + xo * 17 + yo, acc[dyl][t2]);
        }
    }
}

// group = bid&7 -> (b, m-half); kc-major within group (A-chunk temporal reuse).
template<bool PART>
__global__ __launch_bounds__(TPB, 4)
void corr_v11(const float* __restrict__ xpsi,
              float* __restrict__ out, float* __restrict__ part)
{
    __shared__ __align__(16) unsigned char smem[38272];
    const int bid = blockIdx.x;
    const int g8  = bid & 7;
    const int b   = g8 >> 1;
    const int mh  = g8 & 1;
    const int w   = bid >> 3;
    const int kc  = w / 17;
    const int s   = w - kc * 17;
    if (s < 9)
        corr_body<3, PART>(xpsi, out, part, smem, s, 16 * s, 16 * mh, b, kc);
    else if (s < 14)
        corr_body<2, PART>(xpsi, out, part, smem, s, 16 * (s - 9), 16 * mh, b, kc);
    else if (mh == 0)
        corr_body<1, PART>(xpsi, out, part, smem, s, 16 * (s - 14), 0, b, kc);
    else
        corr_body<0, PART>(xpsi, out, part, smem,
                           (s < 16) ? 17 : 18, 8 * (s - 14), 0, b, kc);
}

// Full-range reduce: sums 8 kc slices inside the mask, writes zeros outside.
__global__ __launch_bounds__(256)
void reduce_k(const float* __restrict__ part, float* __restrict__ out)
{
    const int o = blockIdx.x * 256 + threadIdx.x;
    if (o >= NOUT) return;
    const int p  = o / 1156;            // 4*289
    const int r1 = o - p * 1156;
    const int b  = r1 / 289;
    const int s  = r1 - b * 289;
    const int xo = s / 17, yo = s - xo * 17;
    const int pb = p >> 6, cc = p & 63;
    const int j1 = J1T[pb], j2 = J2T[pb];
    const int R  = 1 << j2;
    const int dx = xo <= 8 ? xo : xo - 17;
    const int dy = yo <= 8 ? yo : yo - 17;
    float v = 0.f;
    if (dx >= -R && dx <= R && dy >= -R && dy <= R) {
        const int ch1 = ((cc >> 4) & 3) * 2 + ((cc >> 1) & 1);
        const int ch2 = ((cc >> 2) & 3) * 2 + (cc & 1);
        const int DYN = 2 * R + 1, MV = 8 * (j2 + 1);
        const int ncol = ch2 * DYN + (dx + R);
        const int t = TSTART[j2] + (ncol >> 4);
        const int c = ncol & 15;
        const int m = j1 * 8 + ch1;
        const int S = DYN * MV * 16;
        const float* q = part + TBASE[t]
                       + ((size_t)(b * DYN + (dy + R)) * MV + m) * 16 + c;
        #pragma unroll
        for (int kc = 0; kc < 8; ++kc) v += q[(size_t)kc * 4 * S];
    }
    out[o] = v;
}

extern "C" void kernel_launch(void* const* d_in, const int* in_sizes, int n_in,
                              void* d_out, int out_size, void* d_ws, size_t ws_size,
                              hipStream_t stream) {
    const float* xpsi = (const float*)d_in[0];
    float* out = (float*)d_out;

    if (ws_size >= (size_t)NPART * 4) {
        float* part = (float*)d_ws;
        corr_v11<true><<<1088, TPB, 0, stream>>>(xpsi, out, part);
        reduce_k<<<(NOUT + 255) / 256, 256, 0, stream>>>(part, out);
    } else {
        hipMemsetAsync(d_out, 0, (size_t)out_size * sizeof(float), stream);
        corr_v11<false><<<1088, TPB, 0, stream>>>(xpsi, out, nullptr);
    }
}

// Round 12
// 76.534 us; speedup vs baseline: 1.0022x; 1.0022x over previous
//
#include <hip/hip_runtime.h>

typedef __attribute__((ext_vector_type(8))) short short8;
typedef __attribute__((ext_vector_type(4))) float float4v;

#define TPB 256
#define NPART 3207168            /* partial floats: 8 kc-slices (in-block kh-reduced) */
#define NOUT  739840             /* 640*4*289 */

// per-partial-tile base (floats), 19 tiles. size(t) = 8*4*DYN*MV*16
__device__ __constant__ int TBASE[19] = {
    0, 278528, 557056, 835584, 1114112, 1392640, 1671168, 1949696, 2228224,
    2506752, 2617344, 2727936, 2838528, 2949120,
    3059712, 3100672, 3141632,
    3182592, 3194880};
__device__ __constant__ unsigned char J1T[10] = {0,0,0,0,1,1,1,2,2,3};
__device__ __constant__ unsigned char J2T[10] = {0,1,2,3,1,2,3,2,3,3};
__device__ __constant__ unsigned char TSTART[4] = {17,14,9,0};   // class->first tile

static __device__ __forceinline__ unsigned short f2bf(float f) {
    unsigned int u = __builtin_bit_cast(unsigned int, f);
    u = (u + 0x7FFFu + ((u >> 16) & 1u)) >> 16;     // RNE, data has no NaN
    return (unsigned short)u;
}

// corr[p,b,dx,dy] = sum_{u,v} a[u,v]*b[(u-dx)%128,(v-dy)%128]; |dx|,|dy|<=r=2^j2.
// Wave (dg,kh): dg = dyi half (acc <=9 slots -> 36 VGPR), kh = K half (4 slices/sub).
// kh-pairs cross-wave summed via LDS; fp32->bf16 staged in-kernel (T14 split).
template<int J2, bool PART>
static __device__ __forceinline__ void corr_body(
        const float* __restrict__ xpsi,
        float* __restrict__ out, float* __restrict__ part,
        unsigned char* smem, int tgl, int n0, int moff, int b, int kc)
{
    constexpr int R    = 1 << J2;
    constexpr int DXN  = 2 * R + 1;
    constexpr int DYN  = DXN;
    constexpr int NH   = (DYN + 1) / 2;           // dg=0 count
    constexpr int ND2  = DYN - NH;                // dg=1 count
    constexpr int MV   = 8 * (J2 + 1);
    constexpr int ROWS = 16 + 2 * R;
    constexpr int ABUF = 16 * 256;                // A buffer elements (16r x 2K x 128)
    constexpr int S    = DYN * MV * 16;           // floats per partial slice
    constexpr int W    = (J2 == 0) ? 8 : 16;

    unsigned short* a_lds = (unsigned short*)smem;               // 2 x 8KB
    unsigned short* b_lds = (unsigned short*)(smem + 4 * ABUF);

    const int k0    = kc * 16;
    const int vrows = (MV - moff < 16) ? MV - moff : 16;

    const int ch2lo = n0 / DXN;
    int nhi = n0 + W - 1; if (nhi > 8 * DXN - 1) nhi = 8 * DXN - 1;
    const int nimg = nhi / DXN - ch2lo + 1;

    const int tid  = threadIdx.x;
    const int lane = tid & 63;
    const int wv   = tid >> 6;
    const int kh   = wv & 1;          // K half: slices kh*4 .. kh*4+3
    const int dg   = wv >> 1;         // dyi half
    const int c    = lane & 15;       // N-col / A m-row
    const int g    = lane >> 4;       // K-group

    const int ncol    = n0 + c;
    const bool validn = (ncol < 8 * DXN) && (J2 > 0 || c < 8);
    const int ncc     = validn ? ncol : n0;
    const int ch2     = ncc / DXN;
    const int dxi     = ncc - ch2 * DXN;
    const int dx      = dxi - R;
    const int xo      = dx < 0 ? dx + 17 : dx;
    const int bst     = ((ch2 - ch2lo) * ROWS + (2 * R - dxi)) * 152;

    // ---- A stage, split load/write (T14); 16 rows x [2 K-rows x 128px],
    // 16B-granule swizzle lo=(o&31)^ms ----
    float4 ar[4];
    auto loadA = [&](int sub) {
        #pragma unroll
        for (int it = 0; it < 2; ++it) {
            const int o  = it * TPB + tid;
            const int ms = o >> 5;
            const int lo = (o & 31) ^ ms;
            const int me = moff + ms;
            const int j1 = me >> 3, ch1 = me & 7;
            if (ms < vrows) {
                const float* s = xpsi + ((((size_t)j1*4 + b)*8) + ch1) * 16384
                               + (k0 + sub * 2 + (lo >> 4)) * 128 + ((lo & 15) << 3);
                ar[2*it]   = ((const float4*)s)[0];
                ar[2*it+1] = ((const float4*)s)[1];
            } else {
                ar[2*it] = float4{0.f,0.f,0.f,0.f}; ar[2*it+1] = float4{0.f,0.f,0.f,0.f};
            }
        }
    };
    auto writeA = [&](int bufi) {
        unsigned short* ab = a_lds + bufi * ABUF;
        #pragma unroll
        for (int it = 0; it < 2; ++it) {
            const int o = it * TPB + tid;
            const float4 f0 = ar[2*it], f1 = ar[2*it+1];
            *(ushort4*)(ab + o*8)   = ushort4{f2bf(f0.x),f2bf(f0.y),f2bf(f0.z),f2bf(f0.w)};
            *(ushort4*)(ab + o*8+4) = ushort4{f2bf(f1.x),f2bf(f1.y),f2bf(f1.z),f2bf(f1.w)};
        }
    };

    loadA(0);

    // ---- stage B once: [nimg][ROWS][144 +8pad], col tc <-> src (tc+R-16)&127 ----
    if (J2 >= 2) {
        for (int ci = 0; ci < nimg; ++ci) {
            const float* img = xpsi + ((((size_t)J2*4 + b)*8) + ch2lo + ci) * 16384;
            const int ng2 = ROWS * 36;
            for (int i = tid; i < ng2; i += TPB) {
                const int tr = i / 36, tc = (i - tr * 36) * 4;
                const int sr = (k0 - R + tr) & 127;
                const int sc = (tc + R - 16) & 127;
                const float4 v = *(const float4*)(img + sr * 128 + sc);
                *(ushort4*)(b_lds + (ci * ROWS + tr) * 152 + tc) =
                    ushort4{f2bf(v.x), f2bf(v.y), f2bf(v.z), f2bf(v.w)};
            }
        }
    } else {
        const int tot = nimg * ROWS * 144;
        for (int i = tid; i < tot; i += TPB) {
            const int ci = i / (ROWS * 144);
            const int rr = i - ci * (ROWS * 144);
            const int tr = rr / 144, tc = rr - tr * 144;
            const int sr = (k0 - R + tr) & 127;
            const int sc = (tc + R - 16) & 127;
            b_lds[(ci * ROWS + tr) * 152 + tc] =
                f2bf(xpsi[((((size_t)J2*4 + b)*8) + ch2lo + ci) * 16384 + sr * 128 + sc]);
        }
    }

    writeA(0);

    float4v acc[NH];
    #pragma unroll
    for (int i = 0; i < NH; ++i) acc[i] = (float4v)0.f;

    auto compute = [&](int sub, int bufi) {
        const char* abase = (const char*)(a_lds + bufi * ABUF);
        #pragma unroll
        for (int i2 = 0; i2 < 4; ++i2) {          // K-slice = kh*4 + i2
            const int loff = (((kh << 8) | (i2 << 6) | (g << 4))) ^ (c << 4);
            const short8 af0 = *(const short8*)(abase + c * 512 + loff);

            const unsigned short* bp = b_lds + bst + (sub*2 + kh)*152 + (i2<<5) + (g<<3);
            const uint4 wA = *(const uint4*)bp;
            const uint4 wB = *(const uint4*)(bp + 8);
            const uint4 wC = *(const uint4*)(bp + 16);
            const unsigned int wd[12] = {wA.x,wA.y,wA.z,wA.w, wB.x,wB.y,wB.z,wB.w,
                                         wC.x,wC.y,wC.z,wC.w};
            // uniform dg branch keeps extraction constants compile-time (rule #20)
            if (dg == 0) {
                #pragma unroll
                for (int dyl = 0; dyl < NH; ++dyl) {
                    const int dyi = dyl;
                    unsigned int o0,o1,o2,o3;
                    if ((dyi & 1) == 0) {
                        const int bb = 8 - (dyi >> 1);
                        o0=wd[bb]; o1=wd[bb+1]; o2=wd[bb+2]; o3=wd[bb+3];
                    } else {
                        const int bb = (15 - dyi) >> 1;
                        o0=(wd[bb]>>16)|(wd[bb+1]<<16);   o1=(wd[bb+1]>>16)|(wd[bb+2]<<16);
                        o2=(wd[bb+2]>>16)|(wd[bb+3]<<16); o3=(wd[bb+3]>>16)|(wd[bb+4]<<16);
                    }
                    union { unsigned int u[4]; short8 s; } bq;
                    bq.u[0]=o0; bq.u[1]=o1; bq.u[2]=o2; bq.u[3]=o3;
                    acc[dyl] = __builtin_amdgcn_mfma_f32_16x16x32_bf16(
                        af0, bq.s, acc[dyl], 0, 0, 0);
                }
            } else {
                #pragma unroll
                for (int dyl = 0; dyl < ND2; ++dyl) {
                    const int dyi = NH + dyl;
                    unsigned int o0,o1,o2,o3;
                    if ((dyi & 1) == 0) {
                        const int bb = 8 - (dyi >> 1);
                        o0=wd[bb]; o1=wd[bb+1]; o2=wd[bb+2]; o3=wd[bb+3];
                    } else {
                        const int bb = (15 - dyi) >> 1;
                        o0=(wd[bb]>>16)|(wd[bb+1]<<16);   o1=(wd[bb+1]>>16)|(wd[bb+2]<<16);
                        o2=(wd[bb+2]>>16)|(wd[bb+3]<<16); o3=(wd[bb+3]>>16)|(wd[bb+4]<<16);
                    }
                    union { unsigned int u[4]; short8 s; } bq;
                    bq.u[0]=o0; bq.u[1]=o1; bq.u[2]=o2; bq.u[3]=o3;
                    acc[dyl] = __builtin_amdgcn_mfma_f32_16x16x32_bf16(
                        af0, bq.s, acc[dyl], 0, 0, 0);
                }
            }
        }
    };

    __syncthreads();
    for (int sub = 0; sub < 8; ++sub) {
        if (sub < 7) loadA(sub + 1);               // issue next loads (regs)
        compute(sub, sub & 1);
        if (sub < 7) writeA((sub + 1) & 1);        // convert+write after compute
        __syncthreads();
    }

    const int nmine = dg ? ND2 : NH;
    const int dy0   = dg ? NH : 0;

    if (PART) {
        // kh-pair reduction via LDS (<=17.4KB), then direct stores
        float* red = (float*)smem;                 // [dg][dyl][lane][4] floats
        float* pt  = part + TBASE[tgl] + (size_t)(kc * 4 + b) * S;
        const int cpart0 = n0 & 15;
        if (kh == 1) {
            #pragma unroll
            for (int dyl = 0; dyl < NH; ++dyl) {
                if (dyl >= nmine) break;
                *(float4v*)(red + ((dg * NH + dyl) * 64 + lane) * 4) = acc[dyl];
            }
        }
        __syncthreads();
        if (kh == 0) {
            #pragma unroll
            for (int dyl = 0; dyl < NH; ++dyl) {
                if (dyl >= nmine) break;
                const float4v s = acc[dyl]
                    + *(const float4v*)(red + ((dg * NH + dyl) * 64 + lane) * 4);
                if (validn) {
                    const int dyi = dy0 + dyl;
                    #pragma unroll
                    for (int t2 = 0; t2 < 4; ++t2) {
                        const int ml = (g << 2) + t2;
                        if (ml < vrows)
                            pt[(dyi * MV + moff + ml) * 16 + cpart0 + c] = s[t2];
                    }
                }
            }
        }
        return;
    }

    if (!validn) return;
    #pragma unroll
    for (int dyl = 0; dyl < NH; ++dyl) {
        if (dyl >= nmine) break;
        const int dyi = dy0 + dyl;
        const int dy = dyi - R;
        const int yo = dy < 0 ? dy + 17 : dy;
        #pragma unroll
        for (int t2 = 0; t2 < 4; ++t2) {
            const int ml = (g << 2) + t2;
            if (ml >= vrows) continue;
            const int m = moff + ml;
            const int j1 = m >> 3, ch1 = m & 7;
            const int pb = ((j1 * (9 - j1)) >> 1) + (J2 - j1);
            const int p  = pb * 64 + ((ch1 >> 1) << 4) + ((ch2 >> 1) << 2)
                         + ((ch1 & 1) << 1) + (ch2 & 1);
            atomicAdd(out + (size_t)(p * 4 + b) * 289 + xo * 17 + yo, acc[dyl][t2]);
        }
    }
}

// group = bid&7 -> (b, m-half); kc-major within group (A-chunk temporal reuse).
// launch_bounds min-waves/EU = 3: VGPR cap 168 (R11's 4 forced a 64-VGPR clamp
// -> acc spilled to scratch -> 112MB HBM writes; this is the single change).
template<bool PART>
__global__ __launch_bounds__(TPB, 3)
void corr_v12(const float* __restrict__ xpsi,
              float* __restrict__ out, float* __restrict__ part)
{
    __shared__ __align__(16) unsigned char smem[38272];
    const int bid = blockIdx.x;
    const int g8  = bid & 7;
    const int b   = g8 >> 1;
    const int mh  = g8 & 1;
    const int w   = bid >> 3;
    const int kc  = w / 17;
    const int s   = w - kc * 17;
    if (s < 9)
        corr_body<3, PART>(xpsi, out, part, smem, s, 16 * s, 16 * mh, b, kc);
    else if (s < 14)
        corr_body<2, PART>(xpsi, out, part, smem, s, 16 * (s - 9), 16 * mh, b, kc);
    else if (mh == 0)
        corr_body<1, PART>(xpsi, out, part, smem, s, 16 * (s - 14), 0, b, kc);
    else
        corr_body<0, PART>(xpsi, out, part, smem,
                           (s < 16) ? 17 : 18, 8 * (s - 14), 0, b, kc);
}

// Full-range reduce: sums 8 kc slices inside the mask, writes zeros outside.
__global__ __launch_bounds__(256)
void reduce_k(const float* __restrict__ part, float* __restrict__ out)
{
    const int o = blockIdx.x * 256 + threadIdx.x;
    if (o >= NOUT) return;
    const int p  = o / 1156;            // 4*289
    const int r1 = o - p * 1156;
    const int b  = r1 / 289;
    const int s  = r1 - b * 289;
    const int xo = s / 17, yo = s - xo * 17;
    const int pb = p >> 6, cc = p & 63;
    const int j1 = J1T[pb], j2 = J2T[pb];
    const int R  = 1 << j2;
    const int dx = xo <= 8 ? xo : xo - 17;
    const int dy = yo <= 8 ? yo : yo - 17;
    float v = 0.f;
    if (dx >= -R && dx <= R && dy >= -R && dy <= R) {
        const int ch1 = ((cc >> 4) & 3) * 2 + ((cc >> 1) & 1);
        const int ch2 = ((cc >> 2) & 3) * 2 + (cc & 1);
        const int DYN = 2 * R + 1, MV = 8 * (j2 + 1);
        const int ncol = ch2 * DYN + (dx + R);
        const int t = TSTART[j2] + (ncol >> 4);
        const int c = ncol & 15;
        const int m = j1 * 8 + ch1;
        const int S = DYN * MV * 16;
        const float* q = part + TBASE[t]
                       + ((size_t)(b * DYN + (dy + R)) * MV + m) * 16 + c;
        #pragma unroll
        for (int kc = 0; kc < 8; ++kc) v += q[(size_t)kc * 4 * S];
    }
    out[o] = v;
}

extern "C" void kernel_launch(void* const* d_in, const int* in_sizes, int n_in,
                              void* d_out, int out_size, void* d_ws, size_t ws_size,
                              hipStream_t stream) {
    const float* xpsi = (const float*)d_in[0];
    float* out = (float*)d_out;

    if (ws_size >= (size_t)NPART * 4) {
        float* part = (float*)d_ws;
        corr_v12<true><<<1088, TPB, 0, stream>>>(xpsi, out, part);
        reduce_k<<<(NOUT + 255) / 256, 256, 0, stream>>>(part, out);
    } else {
        hipMemsetAsync(d_out, 0, (size_t)out_size * sizeof(float), stream);
        corr_v12<false><<<1088, TPB, 0, stream>>>(xpsi, out, nullptr);
    }
}

// Round 13
// 43.720 us; speedup vs baseline: 1.7545x; 1.7506x over previous
//
#include <hip/hip_runtime.h>

typedef __attribute__((ext_vector_type(8))) short short8;
typedef __attribute__((ext_vector_type(4))) float float4v;

#define TPB 256
#define NPART 1603584            /* partial floats: 4 kc-slices (32 K-rows each) */
#define NOUT  739840             /* 640*4*289 */

// per-partial-tile base (floats), 19 tiles. size(t) = 4*4*DYN*MV*16
__device__ __constant__ int TBASE[19] = {
    0, 139264, 278528, 417792, 557056, 696320, 835584, 974848, 1114112,
    1253376, 1308672, 1363968, 1419264, 1474560,
    1529856, 1550336, 1570816,
    1591296, 1597440};
__device__ __constant__ unsigned char J1T[10] = {0,0,0,0,1,1,1,2,2,3};
__device__ __constant__ unsigned char J2T[10] = {0,1,2,3,1,2,3,2,3,3};
__device__ __constant__ unsigned char TSTART[4] = {17,14,9,0};   // class->first tile

static __device__ __forceinline__ unsigned short f2bf(float f) {
    unsigned int u = __builtin_bit_cast(unsigned int, f);
    u = (u + 0x7FFFu + ((u >> 16) & 1u)) >> 16;     // RNE, data has no NaN
    return (unsigned short)u;
}

// corr[p,b,dx,dy] = sum_{u,v} a[u,v]*b[(u-dx)%128,(v-dy)%128]; |dx|,|dy|<=r=2^j2.
// R9 structure, kc-pair merged: block owns 32 K-rows (kc 0..3), B restaged at
// half boundary (window unchanged -> same LDS), acc spans 16 subs in regs.
// Waves split K within a sub (wave wv owns v-col group wv*32); cross-wave sum
// via LDS before one partial store per block.
template<int J2, bool PART>
static __device__ __forceinline__ void corr_body(
        const float* __restrict__ xpsi,
        float* __restrict__ out, float* __restrict__ part,
        unsigned char* smem, int tgl, int n0, int moff, int b, int kc)
{
    constexpr int R    = 1 << J2;
    constexpr int DXN  = 2 * R + 1;
    constexpr int DYN  = DXN;
    constexpr int MV   = 8 * (J2 + 1);
    constexpr int ROWS = 16 + 2 * R;              // B window per 16-K half
    constexpr int ABUF = 16 * 256;                // A buffer elements (16r x 2K x 128)
    constexpr int S    = DYN * MV * 16;           // floats per partial slice
    constexpr int W    = (J2 == 0) ? 8 : 16;

    unsigned short* a_lds = (unsigned short*)smem;               // 2 x 8KB
    unsigned short* b_lds = (unsigned short*)(smem + 4 * ABUF);

    const int k0    = kc * 32;
    const int vrows = (MV - moff < 16) ? MV - moff : 16;

    const int ch2lo = n0 / DXN;
    int nhi = n0 + W - 1; if (nhi > 8 * DXN - 1) nhi = 8 * DXN - 1;
    const int nimg = nhi / DXN - ch2lo + 1;

    const int tid  = threadIdx.x;
    const int lane = tid & 63;
    const int wv   = tid >> 6;
    const int c    = lane & 15;       // N-col / A m-row
    const int g    = lane >> 4;       // K-group

    const int ncol    = n0 + c;
    const bool validn = (ncol < 8 * DXN) && (J2 > 0 || c < 8);
    const int ncc     = validn ? ncol : n0;
    const int ch2     = ncc / DXN;
    const int dxi     = ncc - ch2 * DXN;
    const int dx      = dxi - R;
    const int xo      = dx < 0 ? dx + 17 : dx;
    const int bst     = ((ch2 - ch2lo) * ROWS + (2 * R - dxi)) * 152;

    // ---- A stage, split load/write (T14); 16 rows x [2 K-rows x 128px],
    // 16B-granule swizzle lo=(o&31)^ms; sub = 0..15 over the 32 K-rows ----
    float4 ar[4];
    auto loadA = [&](int sub) {
        #pragma unroll
        for (int it = 0; it < 2; ++it) {
            const int o  = it * TPB + tid;
            const int ms = o >> 5;
            const int lo = (o & 31) ^ ms;
            const int me = moff + ms;
            const int j1 = me >> 3, ch1 = me & 7;
            if (ms < vrows) {
                const float* s = xpsi + ((((size_t)j1*4 + b)*8) + ch1) * 16384
                               + (k0 + sub * 2 + (lo >> 4)) * 128 + ((lo & 15) << 3);
                ar[2*it]   = ((const float4*)s)[0];
                ar[2*it+1] = ((const float4*)s)[1];
            } else {
                ar[2*it] = float4{0.f,0.f,0.f,0.f}; ar[2*it+1] = float4{0.f,0.f,0.f,0.f};
            }
        }
    };
    auto writeA = [&](int bufi) {
        unsigned short* ab = a_lds + bufi * ABUF;
        #pragma unroll
        for (int it = 0; it < 2; ++it) {
            const int o = it * TPB + tid;
            const float4 f0 = ar[2*it], f1 = ar[2*it+1];
            *(ushort4*)(ab + o*8)   = ushort4{f2bf(f0.x),f2bf(f0.y),f2bf(f0.z),f2bf(f0.w)};
            *(ushort4*)(ab + o*8+4) = ushort4{f2bf(f1.x),f2bf(f1.y),f2bf(f1.z),f2bf(f1.w)};
        }
    };

    // ---- B window stage for half h: [nimg][ROWS][144 +8pad], rows
    // (k0 + h*16 - R + tr) & 127, col tc <-> src (tc+R-16)&127 ----
    auto stageB = [&](int h) {
        if (J2 >= 2) {
            for (int ci = 0; ci < nimg; ++ci) {
                const float* img = xpsi + ((((size_t)J2*4 + b)*8) + ch2lo + ci) * 16384;
                const int ng2 = ROWS * 36;
                for (int i = tid; i < ng2; i += TPB) {
                    const int tr = i / 36, tc = (i - tr * 36) * 4;
                    const int sr = (k0 + h * 16 - R + tr) & 127;
                    const int sc = (tc + R - 16) & 127;
                    const float4 v = *(const float4*)(img + sr * 128 + sc);
                    *(ushort4*)(b_lds + (ci * ROWS + tr) * 152 + tc) =
                        ushort4{f2bf(v.x), f2bf(v.y), f2bf(v.z), f2bf(v.w)};
                }
            }
        } else {
            const int tot = nimg * ROWS * 144;
            for (int i = tid; i < tot; i += TPB) {
                const int ci = i / (ROWS * 144);
                const int rr = i - ci * (ROWS * 144);
                const int tr = rr / 144, tc = rr - tr * 144;
                const int sr = (k0 + h * 16 - R + tr) & 127;
                const int sc = (tc + R - 16) & 127;
                b_lds[(ci * ROWS + tr) * 152 + tc] =
                    f2bf(xpsi[((((size_t)J2*4 + b)*8) + ch2lo + ci) * 16384 + sr * 128 + sc]);
            }
        }
    };

    loadA(0);
    stageB(0);
    writeA(0);

    float4v acc[DYN];
    #pragma unroll
    for (int i = 0; i < DYN; ++i) acc[i] = (float4v)0.f;

    auto compute = [&](int s8, int bufi) {
        const char* abase = (const char*)(a_lds + bufi * ABUF);
        #pragma unroll
        for (int i2 = 0; i2 < 2; ++i2) {          // K-row i2 of the sub; wv = v-col group
            const int loff = (((i2 << 8) | (wv << 6) | (g << 4))) ^ (c << 4);
            const short8 af0 = *(const short8*)(abase + c * 512 + loff);

            const unsigned short* bp = b_lds + bst + (s8*2 + i2)*152 + (wv<<5) + (g<<3);
            const uint4 wA = *(const uint4*)bp;
            const uint4 wB = *(const uint4*)(bp + 8);
            const uint4 wC = *(const uint4*)(bp + 16);
            const unsigned int wd[12] = {wA.x,wA.y,wA.z,wA.w, wB.x,wB.y,wB.z,wB.w,
                                         wC.x,wC.y,wC.z,wC.w};
            #pragma unroll
            for (int dyi = 0; dyi < DYN; ++dyi) {
                unsigned int o0,o1,o2,o3;
                if ((dyi & 1) == 0) {
                    const int bb = 8 - (dyi >> 1);
                    o0=wd[bb]; o1=wd[bb+1]; o2=wd[bb+2]; o3=wd[bb+3];
                } else {
                    const int bb = (15 - dyi) >> 1;        // v_alignbit pattern
                    o0=(wd[bb]>>16)|(wd[bb+1]<<16);   o1=(wd[bb+1]>>16)|(wd[bb+2]<<16);
                    o2=(wd[bb+2]>>16)|(wd[bb+3]<<16); o3=(wd[bb+3]>>16)|(wd[bb+4]<<16);
                }
                union { unsigned int u[4]; short8 s; } bq;
                bq.u[0]=o0; bq.u[1]=o1; bq.u[2]=o2; bq.u[3]=o3;
                acc[dyi] = __builtin_amdgcn_mfma_f32_16x16x32_bf16(
                    af0, bq.s, acc[dyi], 0, 0, 0);
            }
        }
    };

    __syncthreads();
    for (int h = 0; h < 2; ++h) {
        for (int s8 = 0; s8 < 8; ++s8) {
            const int sub = h * 8 + s8;
            if (sub < 15) loadA(sub + 1);          // issue next loads (regs)
            compute(s8, sub & 1);
            if (sub < 15) writeA((sub + 1) & 1);   // convert+write after compute
            __syncthreads();
        }
        if (h == 0) {                               // restage B for the second half
            stageB(1);
            __syncthreads();
        }
    }

    if (PART) {
        // in-block cross-wave reduction via LDS (reuses smem), then plain stores.
        // ALL threads participate in barriers; validity re-derived per item.
        constexpr int NG  = (DYN < 9) ? DYN : 9;          // dyi per phase (36,864B max)
        constexpr int NPH = (DYN + NG - 1) / NG;
        float* red = (float*)smem;                         // [wv][dl][lane][4] floats
        float* pt  = part + TBASE[tgl] + (size_t)(kc * 4 + b) * S;
        const int cpart0 = n0 & 15;
        #pragma unroll
        for (int ph = 0; ph < NPH; ++ph) {
            const int d0 = ph * NG;
            const int nd = (DYN - d0 < NG) ? (DYN - d0) : NG;
            __syncthreads();                               // LDS free for reuse
            #pragma unroll
            for (int dl = 0; dl < NG; ++dl) {
                if (dl >= nd) break;                       // constant after unroll
                *(float4v*)(red + ((wv * NG + dl) * 64 + lane) * 4) = acc[d0 + dl];
            }
            __syncthreads();
            for (int i = tid; i < nd * 64; i += TPB) {
                const int dl = i >> 6;
                const int ln = i & 63;
                const float4v s0 = *(const float4v*)(red + ((0 * NG + dl) * 64 + ln) * 4);
                const float4v s1 = *(const float4v*)(red + ((1 * NG + dl) * 64 + ln) * 4);
                const float4v s2 = *(const float4v*)(red + ((2 * NG + dl) * 64 + ln) * 4);
                const float4v s3 = *(const float4v*)(red + ((3 * NG + dl) * 64 + ln) * 4);
                const float4v s = (s0 + s1) + (s2 + s3);
                const int cc = ln & 15, gg = ln >> 4;
                if ((n0 + cc < 8 * DXN) && (J2 > 0 || cc < 8)) {
                    const int dyi = d0 + dl;
                    #pragma unroll
                    for (int t2 = 0; t2 < 4; ++t2) {
                        const int ml = (gg << 2) + t2;
                        if (ml < vrows)
                            pt[(dyi * MV + moff + ml) * 16 + cpart0 + cc] = s[t2];
                    }
                }
            }
        }
        return;
    }

    if (!validn) return;
    #pragma unroll
    for (int dyi = 0; dyi < DYN; ++dyi) {
        const int dy = dyi - R;
        const int yo = dy < 0 ? dy + 17 : dy;
        #pragma unroll
        for (int t2 = 0; t2 < 4; ++t2) {
            const int ml = (g << 2) + t2;
            if (ml >= vrows) continue;
            const int m = moff + ml;
            const int j1 = m >> 3, ch1 = m & 7;
            const int pb = ((j1 * (9 - j1)) >> 1) + (J2 - j1);
            const int p  = pb * 64 + ((ch1 >> 1) << 4) + ((ch2 >> 1) << 2)
                         + ((ch1 & 1) << 1) + (ch2 & 1);
            atomicAdd(out + (size_t)(p * 4 + b) * 289 + xo * 17 + yo, acc[dyi][t2]);
        }
    }
}

// group = bid&7 -> (b, m-half); kc-major within group. 17 slots x 4 kc x 8 = 544.
template<bool PART>
__global__ __launch_bounds__(TPB, 3)
void corr_v13(const float* __restrict__ xpsi,
              float* __restrict__ out, float* __restrict__ part)
{
    __shared__ __align__(16) unsigned char smem[38272];
    const int bid = blockIdx.x;
    const int g8  = bid & 7;
    const int b   = g8 >> 1;
    const int mh  = g8 & 1;
    const int w   = bid >> 3;
    const int kc  = w / 17;                        // 0..3
    const int s   = w - kc * 17;
    if (s < 9)
        corr_body<3, PART>(xpsi, out, part, smem, s, 16 * s, 16 * mh, b, kc);
    else if (s < 14)
        corr_body<2, PART>(xpsi, out, part, smem, s, 16 * (s - 9), 16 * mh, b, kc);
    else if (mh == 0)
        corr_body<1, PART>(xpsi, out, part, smem, s, 16 * (s - 14), 0, b, kc);
    else
        corr_body<0, PART>(xpsi, out, part, smem,
                           (s < 16) ? 17 : 18, 8 * (s - 14), 0, b, kc);
}

// Full-range reduce: sums 4 kc slices inside the mask, writes zeros outside.
__global__ __launch_bounds__(256)
void reduce_k(const float* __restrict__ part, float* __restrict__ out)
{
    const int o = blockIdx.x * 256 + threadIdx.x;
    if (o >= NOUT) return;
    const int p  = o / 1156;            // 4*289
    const int r1 = o - p * 1156;
    const int b  = r1 / 289;
    const int s  = r1 - b * 289;
    const int xo = s / 17, yo = s - xo * 17;
    const int pb = p >> 6, cc = p & 63;
    const int j1 = J1T[pb], j2 = J2T[pb];
    const int R  = 1 << j2;
    const int dx = xo <= 8 ? xo : xo - 17;
    const int dy = yo <= 8 ? yo : yo - 17;
    float v = 0.f;
    if (dx >= -R && dx <= R && dy >= -R && dy <= R) {
        const int ch1 = ((cc >> 4) & 3) * 2 + ((cc >> 1) & 1);
        const int ch2 = ((cc >> 2) & 3) * 2 + (cc & 1);
        const int DYN = 2 * R + 1, MV = 8 * (j2 + 1);
        const int ncol = ch2 * DYN + (dx + R);
        const int t = TSTART[j2] + (ncol >> 4);
        const int c = ncol & 15;
        const int m = j1 * 8 + ch1;
        const int S = DYN * MV * 16;
        const float* q = part + TBASE[t]
                       + ((size_t)(b * DYN + (dy + R)) * MV + m) * 16 + c;
        #pragma unroll
        for (int kc = 0; kc < 4; ++kc) v += q[(size_t)kc * 4 * S];
    }
    out[o] = v;
}

extern "C" void kernel_launch(void* const* d_in, const int* in_sizes, int n_in,
                              void* d_out, int out_size, void* d_ws, size_t ws_size,
                              hipStream_t stream) {
    const float* xpsi = (const float*)d_in[0];
    float* out = (float*)d_out;

    if (ws_size >= (size_t)NPART * 4) {
        float* part = (float*)d_ws;
        corr_v13<true><<<544, TPB, 0, stream>>>(xpsi, out, part);
        reduce_k<<<(NOUT + 255) / 256, 256, 0, stream>>>(part, out);
    } else {
        hipMemsetAsync(d_out, 0, (size_t)out_size * sizeof(float), stream);
        corr_v13<false><<<544, TPB, 0, stream>>>(xpsi, out, nullptr);
    }
}